// Round 6
// baseline (633.250 us; speedup 1.0000x reference)
//
#include <hip/hip_runtime.h>

#define HH 256
#define WW 256
#define NPIX (HH*WW)
#define LL 16
#define NL (NPIX*LL)
#define PP 136
#define PP2 (PP*2)

typedef _Float16 half_t;
typedef __attribute__((ext_vector_type(8))) _Float16 half8;

// constants (double-evaluated, cast to float -- matches JAX weak-typed scalars)
static constexpr float SIGMAP_F = (float)((1.0/256.0)/(3.0+16.0)); // res/(3+l)
static constexpr float TAUU_F   = (float)((1.0/256.0)/6.0);        // res/6
static constexpr float TAU_F    = (float)(1.0/36.0);               // 1/(2+136/4)

__device__ __forceinline__ float clampf(float x, float lo, float hi){
    return fminf(fmaxf(x, lo), hi);
}

// ---------------- init: u/ubar = f broadcast; px/pt = 0; nrj = 0 -------------
__global__ __launch_bounds__(256) void k_init(const float* __restrict__ f,
    float* __restrict__ u, float* __restrict__ ubar,
    float* __restrict__ px, float* __restrict__ pt, float* __restrict__ nrj)
{
    int tid = blockIdx.x*256 + threadIdx.x;
    if (tid == 0) *nrj = 0.0f;
    if (tid >= NL) return;
    int n = tid >> 4;
    float fv = f[n];
    u[tid] = fv; ubar[tid] = fv;
    px[tid] = 0.0f; px[NL + tid] = 0.0f;
    pt[tid] = 0.0f;
}

// ---------------- prox: dual p update (per pixel,label) ----------------------
__global__ __launch_bounds__(256) void k_prox(const float* __restrict__ f,
    const float* __restrict__ ubar,
    float* __restrict__ px, float* __restrict__ pt,
    const half_t* __restrict__ musum)   // [d][n][z] fp16, full sum
{
    int tid = blockIdx.x*256 + threadIdx.x;
    if (tid >= NL) return;
    int z = tid & (LL-1);
    int n = tid >> 4;
    int i = n >> 8;
    int j = n & (WW-1);

    float ub = ubar[tid];
    float g0 = (i < HH-1) ? (ubar[tid + WW*LL] - ub) * 256.0f : 0.0f;
    float g1 = (j < WW-1) ? (ubar[tid + LL]    - ub) * 256.0f : 0.0f;
    float gt = (z < LL-1) ? (ubar[tid + 1]     - ub) * 16.0f  : 0.0f;

    float ms0 = (float)musum[tid];
    float ms1 = (float)musum[NL + tid];

    float ux0 = px[tid]      + SIGMAP_F * (g0 + ms0);
    float ux1 = px[NL + tid] + SIGMAP_F * (g1 + ms1);
    float ut  = pt[tid]      + SIGMAP_F * gt;

    float klf = (float)(z + 1) * 0.0625f - f[n];
    float pen = 0.5f * klf * klf;            // lmbda = 0.5

    float n2 = ux0*ux0 + ux1*ux1;
    float B  = 0.25f * n2 - pen;
    bool mask = ut < B;

    float px0 = ux0, px1 = ux1, ptn = ut;
    if (mask) {
        float y    = ut + pen;
        float norm = sqrtf(n2);
        float a    = 0.5f * norm;
        float b    = (2.0f/3.0f) * (1.0f - 0.5f*y);
        float v;
        if (b < 0.0f) {
            float sb  = sqrtf(-b);
            float sb3 = sb*sb*sb;
            float dd  = (a - sb3)*(a + sb3);
            if (dd < 0.0f) {
                float ratio = clampf(a / sb3, -1.0f, 1.0f);
                v = 2.0f * sb * cosf(acosf(ratio) * (1.0f/3.0f));
            } else {
                float c = cbrtf(a + sqrtf(dd));
                v = (c == 0.0f) ? 0.0f : (c - b/c);
            }
        } else {
            float dd = a*a + b*b*b;          // >= 0
            float c  = cbrtf(a + sqrtf(dd));
            v = (c == 0.0f) ? 0.0f : (c - b/c);
        }
        if (norm == 0.0f) { px0 = 0.0f; px1 = 0.0f; }
        else              { float s = 2.0f*v/norm; px0 = s*ux0; px1 = s*ux1; }
        ptn = 0.25f*(px0*px0 + px1*px1) - pen;
    }
    px[tid] = px0; px[NL + tid] = px1; pt[tid] = ptn;
}

// ---------------- fused s/mu update + primal u update ------------------------
// Geometry: 512-thread blocks = 8 waves. wave id = row-set h (wave-uniform ->
// no divergence in template dispatch). lane = pix*2 + d (32 pixels x 2 dirs);
// shfl_xor(1) couples d=0/1 for snorm. Set H handles rows {H, 15-H} (17
// combos, balanced, static indices).
// muOld ELIMINATED: mu_k - mu_{k-1} = tau*(sx_{k-1} - t_prev) where t_prev is
// the interval sum of px from the PREVIOUS iteration (fp16 snapshot px_prev).
// So mubar = mu + tau*(sx - t_prev); mu updated IN PLACE.
// Partial musum per wave -> LDS (fp32, swizzled) -> in-block reduction ->
// single fp16 musum buffer (no global partial round-trip).
// Storage (chunk-vectorized, per set H, per (n,d)): 17 elems = chunks 8/8/1:
//   setbase = H*17*2*NPIX; chunk c at +c*16*NPIX + n*16 + d*8; tail at
//   +32*NPIX + n*2 + d.
__device__ __forceinline__ int pidx(int z, int h, int pix, int d) {
    // byte = z*2048 + h*256 + ((pix*8 + d*4) ^ ((z&7)<<5)); return dword index
    return (z*2048 + h*256 + (((pix<<3) + (d<<2)) ^ ((z&7)<<5))) >> 2;
}

template<int H>
__device__ __forceinline__ void do_set(int d, int n,
    const float* __restrict__ p, const float* __restrict__ pp,
    half_t* __restrict__ sx, half_t* __restrict__ mu,
    float* __restrict__ RS, float* __restrict__ C)
{
    constexpr size_t setbase = (size_t)H * 17 * 2 * NPIX;
    const size_t vb   = setbase + (size_t)n*16 + (size_t)d*8;    // chunk0
    const size_t vb1  = vb + (size_t)16*NPIX;                    // chunk1
    const size_t tail = setbase + (size_t)32*NPIX + (size_t)n*2 + (size_t)d;

    half8 sxv0 = *reinterpret_cast<const half8*>(&sx[vb]);
    half8 sxv1 = *reinterpret_cast<const half8*>(&sx[vb1]);
    half8 mCv0 = *reinterpret_cast<const half8*>(&mu[vb]);
    half8 mCv1 = *reinterpret_cast<const half8*>(&mu[vb1]);
    float sxT = (float)sx[tail];
    float mCT = (float)mu[tail];

    half8 sxo0, sxo1, muo0, muo1;
    half_t sxoT = (half_t)0.0f, muoT = (half_t)0.0f;

    float tsum = 0.0f, tprev = 0.0f, rsA = 0.0f, rsB = 0.0f;
    #pragma unroll
    for (int q = 0; q < 17; ++q) {
        const int b = (q <= 15-H) ? H + q : q - 1;   // static under unroll
        float sxval, mCval;
        if (q < 8)       { sxval=(float)sxv0[q];   mCval=(float)mCv0[q]; }
        else if (q < 16) { sxval=(float)sxv1[q-8]; mCval=(float)mCv1[q-8]; }
        else             { sxval=sxT;              mCval=mCT; }

        if (q == 0 || q == 16-H) { tsum = 0.0f; tprev = 0.0f; }  // row start
        tsum  += p[b];
        tprev += pp[b];

        // mubar = mu + tau*(sx_old - t_prev); mx = sx_old - mubar
        float dmu = TAU_F * (sxval - tprev);
        float mx  = sxval - mCval - dmu;
        float mo  = __shfl_xor(mx, 1);
        float snorm = sqrtf(mx*mx + mo*mo);
        if (snorm > 25.6f) mx *= 0.1f / snorm;       // nu*H ; nu/snorm
        float mn = mCval + TAU_F*(mx - tsum);

        if (q < 8)       { sxo0[q]   = (half_t)mx; muo0[q]   = (half_t)mn; }
        else if (q < 16) { sxo1[q-8] = (half_t)mx; muo1[q-8] = (half_t)mn; }
        else             { sxoT      = (half_t)mx; muoT      = (half_t)mn; }

        if (q <= 15-H) rsA += mn; else rsB += mn;
        C[b] += mn;
    }
    RS[H]    = rsA;
    RS[15-H] = rsB;

    *reinterpret_cast<half8*>(&sx[vb])  = sxo0;
    *reinterpret_cast<half8*>(&sx[vb1]) = sxo1;
    *reinterpret_cast<half8*>(&mu[vb])  = muo0;
    *reinterpret_cast<half8*>(&mu[vb1]) = muo1;
    sx[tail] = sxoT;
    mu[tail] = muoT;
}

__global__ __launch_bounds__(512) void k_smu_u(const float* __restrict__ px,
    const float* __restrict__ pt,
    half_t* __restrict__ sx,
    half_t* __restrict__ mu,            // in-place update
    half_t* __restrict__ pxprev,        // fp16 snapshot of previous px
    half_t* __restrict__ musum,         // [d][n][z] fp16 output
    float* __restrict__ u, float* __restrict__ ubar,
    float* __restrict__ nrj, int compute_nrj)
{
    __shared__ float part[8192];   // 32 KB: [z][h][pix][d] fp32, swizzled
    __shared__ float wsum[8];

    int tid  = threadIdx.x;
    int wv   = tid >> 6;          // wave id = row-set h (0..7)
    int lane = tid & 63;
    int pix  = lane >> 1;
    int d    = lane & 1;
    int n    = blockIdx.x*32 + pix;

    // -------- load p (current px, fp32) and pp (prev px, fp16) --------
    float p[LL], pp[LL];
    {
        const float4* pxd = reinterpret_cast<const float4*>(px + (size_t)d*NL + (size_t)n*LL);
        #pragma unroll
        for (int q = 0; q < 4; ++q) {
            float4 a = pxd[q];
            p[4*q+0]=a.x; p[4*q+1]=a.y; p[4*q+2]=a.z; p[4*q+3]=a.w;
        }
        const half8* ppv = reinterpret_cast<const half8*>(pxprev + (size_t)d*NL + (size_t)n*LL);
        half8 v0 = ppv[0], v1 = ppv[1];
        #pragma unroll
        for (int q = 0; q < 8; ++q) { pp[q] = (float)v0[q]; pp[q+8] = (float)v1[q]; }
    }
    __syncthreads();   // all pp reads complete before wave 1 overwrites pxprev

    // -------- phase A: s & mu (per wave = one row set) --------
    float RS[LL], C[LL];
    #pragma unroll
    for (int q = 0; q < LL; ++q) { RS[q]=0.f; C[q]=0.f; }

    if      (wv == 0) do_set<0>(d,n,p,pp,sx,mu,RS,C);
    else if (wv == 1) do_set<1>(d,n,p,pp,sx,mu,RS,C);
    else if (wv == 2) do_set<2>(d,n,p,pp,sx,mu,RS,C);
    else if (wv == 3) do_set<3>(d,n,p,pp,sx,mu,RS,C);
    else if (wv == 4) do_set<4>(d,n,p,pp,sx,mu,RS,C);
    else if (wv == 5) do_set<5>(d,n,p,pp,sx,mu,RS,C);
    else if (wv == 6) do_set<6>(d,n,p,pp,sx,mu,RS,C);
    else              do_set<7>(d,n,p,pp,sx,mu,RS,C);

    // wave 1 snapshots current px -> pxprev (fp16) for the next iteration
    if (wv == 1) {
        half8 o0, o1;
        #pragma unroll
        for (int q = 0; q < 8; ++q) { o0[q] = (half_t)p[q]; o1[q] = (half_t)p[q+8]; }
        half8* dst = reinterpret_cast<half8*>(pxprev + (size_t)d*NL + (size_t)n*LL);
        dst[0] = o0; dst[1] = o1;
    }

    // partial musum for this wave's row set -> LDS
    // ms[0]=RS[0]; ms[z]=ms[z-1]+RS[z]-C[z-1]  (valid on row subsets)
    {
        float m = RS[0];
        part[pidx(0, wv, pix, d)] = m;
        #pragma unroll
        for (int zq = 1; zq < LL; ++zq) {
            m += RS[zq] - C[zq-1];
            part[pidx(zq, wv, pix, d)] = m;
        }
    }
    __syncthreads();

    // -------- reduce partials over h, store fp16 musum --------
    #pragma unroll
    for (int r = 0; r < 2; ++r) {
        int vi  = tid + r*512;           // 1024 values: [pix][d][z]
        int px2 = vi >> 5;
        int d2  = (vi >> 4) & 1;
        int z2  = vi & 15;
        float s = 0.0f;
        #pragma unroll
        for (int hh = 0; hh < 8; ++hh) s += part[pidx(z2, hh, px2, d2)];
        musum[(size_t)d2*NL + (size_t)(blockIdx.x*32 + px2)*LL + z2] = (half_t)s;
    }

    // -------- phase B: primal u update (1 z per thread) --------
    // independent of phase A (depends only on prox outputs)
    {
        int t  = blockIdx.x*512 + tid;   // [0, NL)
        int z  = t & (LL-1);
        int n2 = t >> 4;
        int i2 = n2 >> 8;
        int j2 = n2 & (WW-1);

        float p0c = px[t];
        float p1c = px[NL + t];
        float d0 = ((i2 < HH-1) ? p0c : 0.0f) - ((i2 > 0) ? px[t - WW*LL] : 0.0f);
        float d1 = ((j2 < WW-1) ? p1c : 0.0f) - ((j2 > 0) ? px[NL + t - LL] : 0.0f);
        float ptc = pt[t];
        float dt = ((z < LL-1) ? ptc : 0.0f) - ((z > 0) ? pt[t - 1] : 0.0f);

        float uo = u[t];
        float Dv = uo + TAUU_F * ((d0 + d1) * 256.0f + dt * 16.0f);
        float un = clampf(Dv, 0.0f, 1.0f);
        if (z == 0)     un = 1.0f;
        if (z == LL-1)  un = 0.0f;
        u[t]    = un;
        ubar[t] = 2.0f*un - uo;

        if (compute_nrj) {
            float v = fabsf(un - uo);
            #pragma unroll
            for (int off = 32; off > 0; off >>= 1) v += __shfl_down(v, off);
            if ((tid & 63) == 0) wsum[wv] = v;
            __syncthreads();
            if (tid == 0) {
                float s = 0.0f;
                #pragma unroll
                for (int q = 0; q < 8; ++q) s += wsum[q];
                atomicAdd(nrj, s);
            }
        }
    }
}

// ---------------- tail scalars ----------------------------------------------
__global__ void k_final(const float* __restrict__ nrj, float* __restrict__ out_tail)
{
    if (threadIdx.x == 0) {
        float e = *nrj;
        out_tail[0] = e;
        out_tail[1] = e * (1.0f/1048576.0f);   // nrj / (H*W*1*l)
        out_tail[2] = 0.0f;
    }
}

extern "C" void kernel_launch(void* const* d_in, const int* in_sizes, int n_in,
                              void* d_out, int out_size, void* d_ws, size_t ws_size,
                              hipStream_t stream)
{
    const float* f = (const float*)d_in[0];
    float* out = (float*)d_out;

    char* w = (char*)d_ws;
    size_t off = 0;
    auto allocf = [&](size_t nfloats) {
        float* p = (float*)(w + off);
        off += nfloats * sizeof(float);
        return p;
    };
    auto alloch = [&](size_t nhalf) {
        half_t* p = (half_t*)(w + off);
        off += nhalf * sizeof(half_t);
        return p;
    };
    // fp16 block (memset together): sx, mu, musum, pxprev
    half_t* sx     = alloch((size_t)NPIX * PP2);   // 35.7 MB
    half_t* mu     = alloch((size_t)NPIX * PP2);   // 35.7 MB
    half_t* musum  = alloch(2*(size_t)NL);         // 4.2 MB
    half_t* pxprev = alloch(2*(size_t)NL);         // 4.2 MB
    size_t half_bytes = off;
    float*  px    = allocf(2*(size_t)NL);          // 8.4 MB
    float*  pt    = allocf((size_t)NL);            // 4.2 MB
    float*  u     = allocf((size_t)NL);            // 4.2 MB
    float*  ubar  = allocf((size_t)NL);            // 4.2 MB
    float*  nrj   = allocf(64);
    (void)ws_size; (void)in_sizes; (void)n_in; (void)out_size;

    hipMemsetAsync(sx, 0, half_bytes, stream);
    k_init<<<NL/256, 256, 0, stream>>>(f, u, ubar, px, pt, nrj);

    for (int it = 0; it < 10; ++it) {
        k_prox<<<NL/256, 256, 0, stream>>>(f, ubar, px, pt, musum);
        k_smu_u<<<NPIX/32, 512, 0, stream>>>(px, pt, sx, mu, pxprev, musum,
                                             u, ubar, nrj, it == 0 ? 1 : 0);
    }

    hipMemcpyAsync(out, u, (size_t)NL*sizeof(float), hipMemcpyDeviceToDevice, stream);
    k_final<<<1, 64, 0, stream>>>(nrj, out + NL);
}